// Round 10
// baseline (147.992 us; speedup 1.0000x reference)
//
#include <hip/hip_runtime.h>
#include <cmath>

#define PP 10
#define FF 64
#define BLOCK 256
#define NG 8                       // 16-col groups per wave -> 128 elements/wave
#define EPB ((BLOCK / 64) * NG * 16)   // elements per block = 512
#define PGRID 8                    // prep kernel blocks
#define L2E 1.44269504088896f

typedef float f32x4 __attribute__((ext_vector_type(4)));
typedef _Float16 f16x4 __attribute__((ext_vector_type(4)));
typedef _Float16 h2 __attribute__((ext_vector_type(2)));

struct GeluCoef { float c[5]; };

// ---- ws layout (dword offsets) ----
// NFRAG A-frags (16x16 f16 for v_mfma_f32_16x16x16f16), 128 dw each:
//   F=0,1   : attn (layer l): row=o, col k=j: j<10 -> ln1g[j]*(Wv@Wo)[j][o];
//             j==10 -> c1[o] (bias via ones-row trick); else 0. rows>=10 -> 0
//   F=2..9  : ffn1 [l][m]: row=f'=f-16m, k=j: j<10 -> ln2g[j]*W1[l][j][f];
//             j==10 -> b1eff[f]; else 0
//   F=10..13: ffn2 layer0 [c]: row=o<10, k=kk: W2[0][16c+kk][o]
//   F=14..17: w2c [c]: row=0, k=kk: sum_o W2[1][16c+kk][o]*Wc[o]
//   F=18    : head: row=0, k<10: Wc[k]
// A lane map: row = lane&15, k = 4*(lane>>4)+i (i=0..3 packed low->high)
#define NFRAG 19
#define FB_B2 (NFRAG * 128)   // b2[0] C-layout frag [lane][4] f32, 256 dw
#define F_HC  (FB_B2 + 256)   // f32: bc + Wc.b2[1]

__device__ __forceinline__ float fast_sigmoid(float z) {
    return __builtin_amdgcn_rcpf(1.0f + exp2f(-L2E * z));
}

__device__ __forceinline__ unsigned int pack_h2f(float a, float b) {  // RNE (prep)
    _Float16 ha = (_Float16)a, hb = (_Float16)b;
    unsigned short ua = __builtin_bit_cast(unsigned short, ha);
    unsigned short ub = __builtin_bit_cast(unsigned short, hb);
    return (unsigned int)ua | ((unsigned int)ub << 16);
}

// single-instruction packed convert (RTZ): v_cvt_pkrtz_f16_f32
__device__ __forceinline__ unsigned int pkrtz(float a, float b) {
    return __builtin_bit_cast(unsigned int, __builtin_amdgcn_cvt_pkrtz(a, b));
}

__device__ __forceinline__ h2 h2bcast(float v) {
    _Float16 h = (_Float16)v;
    h2 r; r.x = h; r.y = h; return r;
}

// Butterfly-add on the VALU pipe via gfx950 permlane*_swap BUILTINS (the
// compiler knows these instructions' hazard wait-states; R9's raw inline-asm
// version was invisible to the hazard recognizer -> stale reads -> NaN).
// With both inputs = x, r[0]+r[1] == x[l] + x[l^16] (resp ^32) on every lane.
#if __has_builtin(__builtin_amdgcn_permlane16_swap) && __has_builtin(__builtin_amdgcn_permlane32_swap)
__device__ __forceinline__ float bfly_add16(float x) {
    unsigned u = __builtin_bit_cast(unsigned, x);
    auto r = __builtin_amdgcn_permlane16_swap(u, u, false, false);
    return __builtin_bit_cast(float, (unsigned)r[0]) +
           __builtin_bit_cast(float, (unsigned)r[1]);
}
__device__ __forceinline__ float bfly_add32(float x) {
    unsigned u = __builtin_bit_cast(unsigned, x);
    auto r = __builtin_amdgcn_permlane32_swap(u, u, false, false);
    return __builtin_bit_cast(float, (unsigned)r[0]) +
           __builtin_bit_cast(float, (unsigned)r[1]);
}
#else
// fallback: ds_bpermute path (correct, R8-parity performance)
__device__ __forceinline__ float bfly_add16(float x) { return x + __shfl_xor(x, 16); }
__device__ __forceinline__ float bfly_add32(float x) { return x + __shfl_xor(x, 32); }
#endif

#define MFMA(a, b, c) __builtin_amdgcn_mfma_f32_16x16x16f16((a), (b), (c), 0, 0, 0)

// ======================= prep kernel (8 blocks, grid-stride) =======================
__global__ __launch_bounds__(256) void prep2(
    const float* __restrict__ Wv, const float* __restrict__ bv,
    const float* __restrict__ Wo, const float* __restrict__ bo,
    const float* __restrict__ ln1g, const float* __restrict__ ln1b,
    const float* __restrict__ ln2g, const float* __restrict__ ln2b,
    const float* __restrict__ W1, const float* __restrict__ b1,
    const float* __restrict__ W2, const float* __restrict__ b2,
    const float* __restrict__ Wc, const float* __restrict__ bc,
    float* __restrict__ ws)
{
    const int gt = blockIdx.x * 256 + threadIdx.x;
    const int GSZ = 256 * PGRID;
    unsigned int* wsu = (unsigned int*)ws;

    for (int idx = gt; idx < NFRAG * 128; idx += GSZ) {
        int F = idx >> 7, d = idx & 127;
        int ln = d >> 1, half = d & 1;
        int row = ln & 15;
        int k0 = 4 * (ln >> 4) + 2 * half;
        float v[2] = {0.0f, 0.0f};
        if (F < 2) {                       // attention (+c1 bias column)
            int l = F;
            if (row < PP) {
                for (int kk = 0; kk < 2; ++kk) {
                    int j = k0 + kk;
                    if (j < PP) {
                        float s = 0.0f;
                        for (int m = 0; m < PP; ++m)
                            s += Wv[l*PP*PP + j*PP + m] * Wo[l*PP*PP + m*PP + row];
                        v[kk] = ln1g[l*PP + j] * s;
                    } else if (j == PP) {  // c1[row]
                        float s = bo[l*PP + row];
                        for (int m = 0; m < PP; ++m)
                            s += bv[l*PP + m] * Wo[l*PP*PP + m*PP + row];
                        for (int jj = 0; jj < PP; ++jj) {
                            float ww = 0.0f;
                            for (int m = 0; m < PP; ++m)
                                ww += Wv[l*PP*PP + jj*PP + m] * Wo[l*PP*PP + m*PP + row];
                            s += ln1b[l*PP + jj] * ww;
                        }
                        v[kk] = s;
                    }
                }
            }
        } else if (F < 10) {               // FFN1 (+b1eff bias column)
            int l = (F - 2) >> 2, m = (F - 2) & 3;
            int f = 16 * m + row;
            for (int kk = 0; kk < 2; ++kk) {
                int j = k0 + kk;
                if (j < PP) {
                    v[kk] = ln2g[l*PP + j] * W1[l*PP*FF + j*FF + f];
                } else if (j == PP) {      // b1eff[f]
                    float s = b1[l*FF + f];
                    for (int jj = 0; jj < PP; ++jj)
                        s += ln2b[l*PP + jj] * W1[l*PP*FF + jj*FF + f];
                    v[kk] = s;
                }
            }
        } else if (F < 14) {               // FFN2 layer 0
            int c = F - 10;
            if (row < PP) {
                for (int kk = 0; kk < 2; ++kk) {
                    int f = 16 * c + k0 + kk;
                    v[kk] = W2[f*PP + row];
                }
            }
        } else if (F < 18) {               // w2c (FFN2 layer1 folded with head)
            int c = F - 14;
            if (row == 0) {
                for (int kk = 0; kk < 2; ++kk) {
                    int f = 16 * c + k0 + kk;
                    float s = 0.0f;
                    for (int o = 0; o < PP; ++o) s += W2[FF*PP + f*PP + o] * Wc[o];
                    v[kk] = s;
                }
            }
        } else {                           // head: Wc row
            if (row == 0) {
                for (int kk = 0; kk < 2; ++kk) {
                    int k = k0 + kk;
                    if (k < PP) v[kk] = Wc[k];
                }
            }
        }
        wsu[idx] = pack_h2f(v[0], v[1]);
    }

    // b2 (layer0) frag in C-layout
    for (int idx = gt; idx < 256; idx += GSZ) {
        int ln = idx >> 2, rr = idx & 3;
        int o = 4 * (ln >> 4) + rr;
        ws[FB_B2 + idx] = (o < PP) ? b2[o] : 0.0f;
    }
    if (gt == 0) {
        float s = bc[0];
        for (int o = 0; o < PP; ++o) s += Wc[o] * b2[PP + o];
        ws[F_HC] = s;
    }
}

// ======================= main kernel =======================
// seq lives in MFMA C-layout: column (lane&15) = batch element within a
// 16-element group, rows (lane>>4)*4+r = channel; rows 10-15 kept exactly 0.
// C-layout of one stage == B-frag layout of the next (16x16x16f16): zero
// transposes, zero LDS. Biases ride in A-column k=10 against y-row10==1.
// launch_bounds(256,4): total regs (arch+acc, unified file) capped at 128
// -> 4 waves/SIMD eligible (R8: 52.6->48.6us vs (256,2)'s 2 waves/SIMD).

__device__ __forceinline__ f16x4 ln_pack(f32x4 s, int q) {
    float ls = (s.x + s.y) + (s.z + s.w);
    float lq = fmaf(s.x, s.x, fmaf(s.y, s.y, fmaf(s.z, s.z, s.w * s.w)));
    ls = bfly_add32(bfly_add16(ls));
    lq = bfly_add32(bfly_add16(lq));
    float mu = ls * 0.1f;                       // LN is over the 10 real rows
    float var = fmaf(-mu, mu, lq * 0.1f);
    float rs = __builtin_amdgcn_rsqf(var + 1e-5f);
    float mrs = -mu * rs;
    uint2 u;
    u.x = pkrtz(fmaf(s.x, rs, mrs), fmaf(s.y, rs, mrs));
    unsigned int hi = pkrtz(fmaf(s.z, rs, mrs), fmaf(s.w, rs, mrs));
    // row 10 (q==2, low half of u.y) forced to 1.0 -> bias column; row 11 = 0
    u.y = (q == 2) ? 0x00003C00u : hi;
    return __builtin_bit_cast(f16x4, u);
}

__device__ __forceinline__ f16x4 gelu_pack(f32x4 tv, h2 G0, h2 G1, h2 G2, h2 G3,
                                           h2 G4, h2 HLF) {
    h2 X0 = __builtin_bit_cast(h2, pkrtz(tv.x, tv.y));
    h2 X1 = __builtin_bit_cast(h2, pkrtz(tv.z, tv.w));
    h2 S0 = X0 * X0, S1 = X1 * X1;
    h2 P0 = S0 * G4 + G3, P1 = S1 * G4 + G3;
    P0 = S0 * P0 + G2; P1 = S1 * P1 + G2;
    P0 = S0 * P0 + G1; P1 = S1 * P1 + G1;
    P0 = S0 * P0 + G0; P1 = S1 * P1 + G0;
    h2 H0 = X0 * P0 + HLF, H1 = X1 * P1 + HLF;
    h2 U0 = X0 * H0, U1 = X1 * H1;
    uint2 u;
    u.x = __builtin_bit_cast(unsigned int, U0);
    u.y = __builtin_bit_cast(unsigned int, U1);
    return __builtin_bit_cast(f16x4, u);
}

// features for one 16-col group: seq[r] = exp2(dot(x, 2*l2e*proto) - l2e*x2 - l2e*p2)
__device__ __forceinline__ void feat4(f32x4* sg, float4 xa, float4 xb,
                                      const float4* pa, const float4* pb,
                                      const float* mp2) {
    float x2 = xa.x*xa.x + xa.y*xa.y + xa.z*xa.z + xa.w*xa.w
             + xb.x*xb.x + xb.y*xb.y + xb.z*xb.z + xb.w*xb.w;
    float xc = -L2E * x2;
#pragma unroll
    for (int r = 0; r < 4; ++r) {
        float s = xc + mp2[r];               // rows>=10: -1e30 -> exp2 -> exact 0
        s = fmaf(xa.x, pa[r].x, s); s = fmaf(xa.y, pa[r].y, s);
        s = fmaf(xa.z, pa[r].z, s); s = fmaf(xa.w, pa[r].w, s);
        s = fmaf(xb.x, pb[r].x, s); s = fmaf(xb.y, pb[r].y, s);
        s = fmaf(xb.z, pb[r].z, s); s = fmaf(xb.w, pb[r].w, s);
        (*sg)[r] = exp2f(s);
    }
}

__global__ __launch_bounds__(BLOCK, 4) void hq_mfma(
    const float* __restrict__ x, const float* __restrict__ protos,
    const float* __restrict__ ws, float* __restrict__ out, int B, GeluCoef gc)
{
    const int t = threadIdx.x;
    const int lane = t & 63;
    const int q = lane >> 4;
    const int col = lane & 15;
    const int wbase = blockIdx.x * EPB + (t >> 6) * (NG * 16);
    const bool fullblk = (wbase + NG * 16) <= B;   // wave-uniform

    const uint2* fr = (const uint2*)ws;
    const f32x4* wv4 = (const f32x4*)ws;
    f32x4 zero4 = {0.0f, 0.0f, 0.0f, 0.0f};

    // ---- kernel features directly in C-layout (protos in short-lived regs) ----
    const float4* x4 = (const float4*)x;
    f32x4 seq[NG];
    {
        const float4* p4 = (const float4*)protos;
        float4 pa[4], pb[4];
        float mp2[4];
#pragma unroll
        for (int r = 0; r < 4; ++r) {
            int p = 4 * q + r;
            int pc = (p < PP) ? p : 0;
            float4 a = p4[pc * 2], b = p4[pc * 2 + 1];
            float s2 = a.x*a.x + a.y*a.y + a.z*a.z + a.w*a.w
                     + b.x*b.x + b.y*b.y + b.z*b.z + b.w*b.w;
            mp2[r] = (p < PP) ? (-L2E * s2) : -1e30f;
            const float TW = 2.0f * L2E;
            pa[r].x = TW*a.x; pa[r].y = TW*a.y; pa[r].z = TW*a.z; pa[r].w = TW*a.w;
            pb[r].x = TW*b.x; pb[r].y = TW*b.y; pb[r].z = TW*b.z; pb[r].w = TW*b.w;
        }
        if (fullblk) {
            const float4* xb4 = x4 + 2 * (size_t)(wbase + col);
#pragma unroll
            for (int g = 0; g < NG; ++g)
                feat4(&seq[g], xb4[32 * g], xb4[32 * g + 1], pa, pb, mp2);
        } else {
#pragma unroll
            for (int g = 0; g < NG; ++g) {
                int e = wbase + g * 16 + col;
                if (e >= B) e = B - 1;
                feat4(&seq[g], x4[e * 2], x4[e * 2 + 1], pa, pb, mp2);
            }
        }
    }

    const h2 GC0 = h2bcast(gc.c[0]);
    const h2 GC1 = h2bcast(gc.c[1]);
    const h2 GC2 = h2bcast(gc.c[2]);
    const h2 GC3 = h2bcast(gc.c[3]);
    const h2 GC4 = h2bcast(gc.c[4]);
    const h2 HLF = h2bcast(0.5f);

    // ================= layer 0 (frags scoped; one fused loop over g) =========
    {
        f16x4 aat = __builtin_bit_cast(f16x4, fr[0 * 64 + lane]);
        f16x4 af1[4], af2[4];
#pragma unroll
        for (int m = 0; m < 4; ++m)
            af1[m] = __builtin_bit_cast(f16x4, fr[(2 + m) * 64 + lane]);
#pragma unroll
        for (int c = 0; c < 4; ++c)
            af2[c] = __builtin_bit_cast(f16x4, fr[(10 + c) * 64 + lane]);
        f32x4 b2f = wv4[FB_B2 / 4 + lane];

#pragma unroll
        for (int g = 0; g < NG; ++g) {
            f16x4 y = ln_pack(seq[g], q);
            seq[g] = MFMA(aat, y, seq[g]);           // attn + residual (C-in)
            y = ln_pack(seq[g], q);
            f32x4 t0 = MFMA(af1[0], y, zero4);
            f32x4 t1 = MFMA(af1[1], y, zero4);
            f32x4 t2 = MFMA(af1[2], y, zero4);
            f32x4 t3 = MFMA(af1[3], y, zero4);
            f16x4 u0 = gelu_pack(t0, GC0, GC1, GC2, GC3, GC4, HLF);
            f16x4 u1 = gelu_pack(t1, GC0, GC1, GC2, GC3, GC4, HLF);
            f16x4 u2 = gelu_pack(t2, GC0, GC1, GC2, GC3, GC4, HLF);
            f16x4 u3 = gelu_pack(t3, GC0, GC1, GC2, GC3, GC4, HLF);
            // FFN2 as two 2-deep chains (residual in oA, b2 in oB)
            f32x4 oA = MFMA(af2[0], u0, seq[g]);
            oA = MFMA(af2[1], u1, oA);
            f32x4 oB = MFMA(af2[2], u2, b2f);
            oB = MFMA(af2[3], u3, oB);
            seq[g] = oA + oB;
        }
    }

    // ================= layer 1 (frags scoped; head fused) =====================
    {
        f16x4 aat = __builtin_bit_cast(f16x4, fr[1 * 64 + lane]);
        f16x4 af1[4], aw2c[4], ahead;
#pragma unroll
        for (int m = 0; m < 4; ++m)
            af1[m] = __builtin_bit_cast(f16x4, fr[(6 + m) * 64 + lane]);
#pragma unroll
        for (int c = 0; c < 4; ++c)
            aw2c[c] = __builtin_bit_cast(f16x4, fr[(14 + c) * 64 + lane]);
        ahead = __builtin_bit_cast(f16x4, fr[18 * 64 + lane]);
        float hc = ws[F_HC];
        f32x4 zi = zero4;
        if (lane < 16) zi.x = hc;     // z rides in row 0

#pragma unroll
        for (int g = 0; g < NG; ++g) {
            f16x4 y = ln_pack(seq[g], q);
            seq[g] = MFMA(aat, y, seq[g]);
            y = ln_pack(seq[g], q);
            f32x4 t0 = MFMA(af1[0], y, zero4);
            f32x4 t1 = MFMA(af1[1], y, zero4);
            f32x4 t2 = MFMA(af1[2], y, zero4);
            f32x4 t3 = MFMA(af1[3], y, zero4);
            f16x4 u0 = gelu_pack(t0, GC0, GC1, GC2, GC3, GC4, HLF);
            f16x4 u1 = gelu_pack(t1, GC0, GC1, GC2, GC3, GC4, HLF);
            f16x4 u2 = gelu_pack(t2, GC0, GC1, GC2, GC3, GC4, HLF);
            f16x4 u3 = gelu_pack(t3, GC0, GC1, GC2, GC3, GC4, HLF);
            // z = hc + w2c.up + Wc.seq as two parallel chains (2 + 3 deep)
            f32x4 zcA = MFMA(aw2c[0], u0, zi);
            zcA = MFMA(aw2c[1], u1, zcA);
            f32x4 zcB = MFMA(aw2c[2], u2, zero4);
            zcB = MFMA(aw2c[3], u3, zcB);
            uint2 sh;
            sh.x = pkrtz(seq[g].x, seq[g].y);
            sh.y = pkrtz(seq[g].z, seq[g].w);       // rows>=10 are exact 0
            zcB = MFMA(ahead, __builtin_bit_cast(f16x4, sh), zcB);
            float r = fast_sigmoid(zcA.x + zcB.x);  // row 0, valid in q==0 lanes
            if (q == 0) {
                int e0 = wbase + g * 16 + col;
                if (fullblk) out[e0] = r;           // 16 contiguous f32 per group
                else if (e0 < B) out[e0] = r;
            }
        }
    }
}

extern "C" void kernel_launch(void* const* d_in, const int* in_sizes, int n_in,
                              void* d_out, int out_size, void* d_ws, size_t ws_size,
                              hipStream_t stream) {
    const float* x      = (const float*)d_in[0];
    const float* protos = (const float*)d_in[1];
    // d_in[2..5] = Wq,bq,Wk,bk — dead (seq_len==1 => softmax==1 => o==v)
    const float* Wv   = (const float*)d_in[6];
    const float* bv   = (const float*)d_in[7];
    const float* Wo   = (const float*)d_in[8];
    const float* bo   = (const float*)d_in[9];
    const float* ln1g = (const float*)d_in[10];
    const float* ln1b = (const float*)d_in[11];
    const float* ln2g = (const float*)d_in[12];
    const float* ln2b = (const float*)d_in[13];
    const float* W1   = (const float*)d_in[14];
    const float* b1   = (const float*)d_in[15];
    const float* W2   = (const float*)d_in[16];
    const float* b2   = (const float*)d_in[17];
    const float* Wc   = (const float*)d_in[18];
    const float* bc   = (const float*)d_in[19];
    float* out = (float*)d_out;
    float* ws  = (float*)d_ws;

    // gelu poly coefficients (host-side, identical every call; graph-capture-safe)
    GeluCoef gcoef;
    {
        const double PI = 3.14159265358979323846;
        const double cc = 0.7978845608028654, aa = 0.044715;
        double sv[5], gd[5];
        for (int k = 0; k < 5; ++k) {
            double tk = 1.85 + 1.85 * std::cos((2 * k + 1) * PI / 10.0);
            sv[k] = tk * tk;
            gd[k] = std::tanh(cc * (tk + aa * tk * tk * tk)) / tk;
        }
        for (int j = 1; j < 5; ++j)
            for (int i = 4; i >= j; --i)
                gd[i] = (gd[i] - gd[i - 1]) / (sv[i] - sv[i - j]);
        double c[5] = {0, 0, 0, 0, 0};
        c[0] = gd[4];
        for (int k = 3; k >= 0; --k) {
            for (int i = 4; i >= 1; --i) c[i] = c[i - 1] - sv[k] * c[i];
            c[0] = -sv[k] * c[0] + gd[k];
        }
        for (int i = 0; i < 5; ++i) gcoef.c[i] = (float)(0.5 * c[i]);
    }

    prep2<<<PGRID, 256, 0, stream>>>(Wv, bv, Wo, bo, ln1g, ln1b, ln2g, ln2b,
                                     W1, b1, W2, b2, Wc, bc, ws);

    const int B = in_sizes[0] / 8;
    const int grid = (B + EPB - 1) / EPB;   // 512 elements per block
    hq_mfma<<<grid, BLOCK, 0, stream>>>(x, protos, ws, out, B, gcoef);
}

// Round 11
// 145.132 us; speedup vs baseline: 1.0197x; 1.0197x over previous
//
#include <hip/hip_runtime.h>
#include <cmath>

#define PP 10
#define FF 64
#define BLOCK 256
#define NG 6                       // 16-col groups per wave -> 96 elements/wave
                                   // (8 -> 6: seq live set 32->24 regs kills the
                                   // R8 marginal spill; grid 1954->2605 smooths
                                   // per-CU residency ramp/tail)
#define EPB ((BLOCK / 64) * NG * 16)   // elements per block = 384
#define PGRID 8                    // prep kernel blocks
#define L2E 1.44269504088896f

typedef float f32x4 __attribute__((ext_vector_type(4)));
typedef _Float16 f16x4 __attribute__((ext_vector_type(4)));
typedef _Float16 h2 __attribute__((ext_vector_type(2)));

struct GeluCoef { float c[5]; };

// ---- ws layout (dword offsets) ----
// NFRAG A-frags (16x16 f16 for v_mfma_f32_16x16x16f16), 128 dw each:
//   F=0,1   : attn (layer l): row=o, col k=j: j<10 -> ln1g[j]*(Wv@Wo)[j][o];
//             j==10 -> c1[o] (bias via ones-row trick); else 0. rows>=10 -> 0
//   F=2..9  : ffn1 [l][m]: row=f'=f-16m, k=j: j<10 -> ln2g[j]*W1[l][j][f];
//             j==10 -> b1eff[f]; else 0
//   F=10..13: ffn2 layer0 [c]: row=o<10, k=kk: W2[0][16c+kk][o]
//   F=14..17: w2c [c]: row=0, k=kk: sum_o W2[1][16c+kk][o]*Wc[o]
//   F=18    : head: row=0, k<10: Wc[k]
// A lane map: row = lane&15, k = 4*(lane>>4)+i (i=0..3 packed low->high)
#define NFRAG 19
#define FB_B2 (NFRAG * 128)   // b2[0] C-layout frag [lane][4] f32, 256 dw
#define F_HC  (FB_B2 + 256)   // f32: bc + Wc.b2[1]

__device__ __forceinline__ float fast_sigmoid(float z) {
    return __builtin_amdgcn_rcpf(1.0f + exp2f(-L2E * z));
}

__device__ __forceinline__ unsigned int pack_h2f(float a, float b) {  // RNE (prep)
    _Float16 ha = (_Float16)a, hb = (_Float16)b;
    unsigned short ua = __builtin_bit_cast(unsigned short, ha);
    unsigned short ub = __builtin_bit_cast(unsigned short, hb);
    return (unsigned int)ua | ((unsigned int)ub << 16);
}

// single-instruction packed convert (RTZ): v_cvt_pkrtz_f16_f32
__device__ __forceinline__ unsigned int pkrtz(float a, float b) {
    return __builtin_bit_cast(unsigned int, __builtin_amdgcn_cvt_pkrtz(a, b));
}

__device__ __forceinline__ h2 h2bcast(float v) {
    _Float16 h = (_Float16)v;
    h2 r; r.x = h; r.y = h; return r;
}

// Cross-lane butterfly adds via ds_bpermute (__shfl_xor). R10 measured the
// permlane*_swap VALU-pipe variant as a ~4% REGRESSION: shuffle latency is
// already hidden at ~2.5 waves/SIMD; the kernel is VALU issue-count bound,
// and permlane added v_mov copies. Keep the DS-pipe version.
__device__ __forceinline__ float bfly_add16(float x) { return x + __shfl_xor(x, 16); }
__device__ __forceinline__ float bfly_add32(float x) { return x + __shfl_xor(x, 32); }

#define MFMA(a, b, c) __builtin_amdgcn_mfma_f32_16x16x16f16((a), (b), (c), 0, 0, 0)

// ======================= prep kernel (8 blocks, grid-stride) =======================
__global__ __launch_bounds__(256) void prep2(
    const float* __restrict__ Wv, const float* __restrict__ bv,
    const float* __restrict__ Wo, const float* __restrict__ bo,
    const float* __restrict__ ln1g, const float* __restrict__ ln1b,
    const float* __restrict__ ln2g, const float* __restrict__ ln2b,
    const float* __restrict__ W1, const float* __restrict__ b1,
    const float* __restrict__ W2, const float* __restrict__ b2,
    const float* __restrict__ Wc, const float* __restrict__ bc,
    float* __restrict__ ws)
{
    const int gt = blockIdx.x * 256 + threadIdx.x;
    const int GSZ = 256 * PGRID;
    unsigned int* wsu = (unsigned int*)ws;

    for (int idx = gt; idx < NFRAG * 128; idx += GSZ) {
        int F = idx >> 7, d = idx & 127;
        int ln = d >> 1, half = d & 1;
        int row = ln & 15;
        int k0 = 4 * (ln >> 4) + 2 * half;
        float v[2] = {0.0f, 0.0f};
        if (F < 2) {                       // attention (+c1 bias column)
            int l = F;
            if (row < PP) {
                for (int kk = 0; kk < 2; ++kk) {
                    int j = k0 + kk;
                    if (j < PP) {
                        float s = 0.0f;
                        for (int m = 0; m < PP; ++m)
                            s += Wv[l*PP*PP + j*PP + m] * Wo[l*PP*PP + m*PP + row];
                        v[kk] = ln1g[l*PP + j] * s;
                    } else if (j == PP) {  // c1[row]
                        float s = bo[l*PP + row];
                        for (int m = 0; m < PP; ++m)
                            s += bv[l*PP + m] * Wo[l*PP*PP + m*PP + row];
                        for (int jj = 0; jj < PP; ++jj) {
                            float ww = 0.0f;
                            for (int m = 0; m < PP; ++m)
                                ww += Wv[l*PP*PP + jj*PP + m] * Wo[l*PP*PP + m*PP + row];
                            s += ln1b[l*PP + jj] * ww;
                        }
                        v[kk] = s;
                    }
                }
            }
        } else if (F < 10) {               // FFN1 (+b1eff bias column)
            int l = (F - 2) >> 2, m = (F - 2) & 3;
            int f = 16 * m + row;
            for (int kk = 0; kk < 2; ++kk) {
                int j = k0 + kk;
                if (j < PP) {
                    v[kk] = ln2g[l*PP + j] * W1[l*PP*FF + j*FF + f];
                } else if (j == PP) {      // b1eff[f]
                    float s = b1[l*FF + f];
                    for (int jj = 0; jj < PP; ++jj)
                        s += ln2b[l*PP + jj] * W1[l*PP*FF + jj*FF + f];
                    v[kk] = s;
                }
            }
        } else if (F < 14) {               // FFN2 layer 0
            int c = F - 10;
            if (row < PP) {
                for (int kk = 0; kk < 2; ++kk) {
                    int f = 16 * c + k0 + kk;
                    v[kk] = W2[f*PP + row];
                }
            }
        } else if (F < 18) {               // w2c (FFN2 layer1 folded with head)
            int c = F - 14;
            if (row == 0) {
                for (int kk = 0; kk < 2; ++kk) {
                    int f = 16 * c + k0 + kk;
                    float s = 0.0f;
                    for (int o = 0; o < PP; ++o) s += W2[FF*PP + f*PP + o] * Wc[o];
                    v[kk] = s;
                }
            }
        } else {                           // head: Wc row
            if (row == 0) {
                for (int kk = 0; kk < 2; ++kk) {
                    int k = k0 + kk;
                    if (k < PP) v[kk] = Wc[k];
                }
            }
        }
        wsu[idx] = pack_h2f(v[0], v[1]);
    }

    // b2 (layer0) frag in C-layout
    for (int idx = gt; idx < 256; idx += GSZ) {
        int ln = idx >> 2, rr = idx & 3;
        int o = 4 * (ln >> 4) + rr;
        ws[FB_B2 + idx] = (o < PP) ? b2[o] : 0.0f;
    }
    if (gt == 0) {
        float s = bc[0];
        for (int o = 0; o < PP; ++o) s += Wc[o] * b2[PP + o];
        ws[F_HC] = s;
    }
}

// ======================= main kernel =======================
// seq lives in MFMA C-layout: column (lane&15) = batch element within a
// 16-element group, rows (lane>>4)*4+r = channel; rows 10-15 kept exactly 0.
// C-layout of one stage == B-frag layout of the next (16x16x16f16): zero
// transposes, zero LDS. Biases ride in A-column k=10 against y-row10==1.
// launch_bounds(256,4): total regs (arch+acc, unified file) capped at 128
// -> 4 waves/SIMD eligible (R8: 52.6->48.6us vs (256,2)'s 2 waves/SIMD).

__device__ __forceinline__ f16x4 ln_pack(f32x4 s, int q) {
    float ls = (s.x + s.y) + (s.z + s.w);
    float lq = fmaf(s.x, s.x, fmaf(s.y, s.y, fmaf(s.z, s.z, s.w * s.w)));
    ls = bfly_add32(bfly_add16(ls));
    lq = bfly_add32(bfly_add16(lq));
    float mu = ls * 0.1f;                       // LN is over the 10 real rows
    float var = fmaf(-mu, mu, lq * 0.1f);
    float rs = __builtin_amdgcn_rsqf(var + 1e-5f);
    float mrs = -mu * rs;
    uint2 u;
    u.x = pkrtz(fmaf(s.x, rs, mrs), fmaf(s.y, rs, mrs));
    unsigned int hi = pkrtz(fmaf(s.z, rs, mrs), fmaf(s.w, rs, mrs));
    // row 10 (q==2, low half of u.y) forced to 1.0 -> bias column; row 11 = 0
    u.y = (q == 2) ? 0x00003C00u : hi;
    return __builtin_bit_cast(f16x4, u);
}

__device__ __forceinline__ f16x4 gelu_pack(f32x4 tv, h2 G0, h2 G1, h2 G2, h2 G3,
                                           h2 G4, h2 HLF) {
    h2 X0 = __builtin_bit_cast(h2, pkrtz(tv.x, tv.y));
    h2 X1 = __builtin_bit_cast(h2, pkrtz(tv.z, tv.w));
    h2 S0 = X0 * X0, S1 = X1 * X1;
    h2 P0 = S0 * G4 + G3, P1 = S1 * G4 + G3;
    P0 = S0 * P0 + G2; P1 = S1 * P1 + G2;
    P0 = S0 * P0 + G1; P1 = S1 * P1 + G1;
    P0 = S0 * P0 + G0; P1 = S1 * P1 + G0;
    h2 H0 = X0 * P0 + HLF, H1 = X1 * P1 + HLF;
    h2 U0 = X0 * H0, U1 = X1 * H1;
    uint2 u;
    u.x = __builtin_bit_cast(unsigned int, U0);
    u.y = __builtin_bit_cast(unsigned int, U1);
    return __builtin_bit_cast(f16x4, u);
}

// features for one 16-col group: seq[r] = exp2(dot(x, 2*l2e*proto) - l2e*x2 - l2e*p2)
__device__ __forceinline__ void feat4(f32x4* sg, float4 xa, float4 xb,
                                      const float4* pa, const float4* pb,
                                      const float* mp2) {
    float x2 = xa.x*xa.x + xa.y*xa.y + xa.z*xa.z + xa.w*xa.w
             + xb.x*xb.x + xb.y*xb.y + xb.z*xb.z + xb.w*xb.w;
    float xc = -L2E * x2;
#pragma unroll
    for (int r = 0; r < 4; ++r) {
        float s = xc + mp2[r];               // rows>=10: -1e30 -> exp2 -> exact 0
        s = fmaf(xa.x, pa[r].x, s); s = fmaf(xa.y, pa[r].y, s);
        s = fmaf(xa.z, pa[r].z, s); s = fmaf(xa.w, pa[r].w, s);
        s = fmaf(xb.x, pb[r].x, s); s = fmaf(xb.y, pb[r].y, s);
        s = fmaf(xb.z, pb[r].z, s); s = fmaf(xb.w, pb[r].w, s);
        (*sg)[r] = exp2f(s);
    }
}

__global__ __launch_bounds__(BLOCK, 4) void hq_mfma(
    const float* __restrict__ x, const float* __restrict__ protos,
    const float* __restrict__ ws, float* __restrict__ out, int B, GeluCoef gc)
{
    const int t = threadIdx.x;
    const int lane = t & 63;
    const int q = lane >> 4;
    const int col = lane & 15;
    const int wbase = blockIdx.x * EPB + (t >> 6) * (NG * 16);
    const bool fullblk = (wbase + NG * 16) <= B;   // wave-uniform

    const uint2* fr = (const uint2*)ws;
    const f32x4* wv4 = (const f32x4*)ws;
    f32x4 zero4 = {0.0f, 0.0f, 0.0f, 0.0f};

    // ---- kernel features directly in C-layout (protos in short-lived regs) ----
    const float4* x4 = (const float4*)x;
    f32x4 seq[NG];
    {
        const float4* p4 = (const float4*)protos;
        float4 pa[4], pb[4];
        float mp2[4];
#pragma unroll
        for (int r = 0; r < 4; ++r) {
            int p = 4 * q + r;
            int pc = (p < PP) ? p : 0;
            float4 a = p4[pc * 2], b = p4[pc * 2 + 1];
            float s2 = a.x*a.x + a.y*a.y + a.z*a.z + a.w*a.w
                     + b.x*b.x + b.y*b.y + b.z*b.z + b.w*b.w;
            mp2[r] = (p < PP) ? (-L2E * s2) : -1e30f;
            const float TW = 2.0f * L2E;
            pa[r].x = TW*a.x; pa[r].y = TW*a.y; pa[r].z = TW*a.z; pa[r].w = TW*a.w;
            pb[r].x = TW*b.x; pb[r].y = TW*b.y; pb[r].z = TW*b.z; pb[r].w = TW*b.w;
        }
        if (fullblk) {
            const float4* xb4 = x4 + 2 * (size_t)(wbase + col);
#pragma unroll
            for (int g = 0; g < NG; ++g)
                feat4(&seq[g], xb4[32 * g], xb4[32 * g + 1], pa, pb, mp2);
        } else {
#pragma unroll
            for (int g = 0; g < NG; ++g) {
                int e = wbase + g * 16 + col;
                if (e >= B) e = B - 1;
                feat4(&seq[g], x4[e * 2], x4[e * 2 + 1], pa, pb, mp2);
            }
        }
    }

    const h2 GC0 = h2bcast(gc.c[0]);
    const h2 GC1 = h2bcast(gc.c[1]);
    const h2 GC2 = h2bcast(gc.c[2]);
    const h2 GC3 = h2bcast(gc.c[3]);
    const h2 GC4 = h2bcast(gc.c[4]);
    const h2 HLF = h2bcast(0.5f);

    // ================= layer 0 (frags scoped; one fused loop over g) =========
    {
        f16x4 aat = __builtin_bit_cast(f16x4, fr[0 * 64 + lane]);
        f16x4 af1[4], af2[4];
#pragma unroll
        for (int m = 0; m < 4; ++m)
            af1[m] = __builtin_bit_cast(f16x4, fr[(2 + m) * 64 + lane]);
#pragma unroll
        for (int c = 0; c < 4; ++c)
            af2[c] = __builtin_bit_cast(f16x4, fr[(10 + c) * 64 + lane]);
        f32x4 b2f = wv4[FB_B2 / 4 + lane];

#pragma unroll
        for (int g = 0; g < NG; ++g) {
            f16x4 y = ln_pack(seq[g], q);
            seq[g] = MFMA(aat, y, seq[g]);           // attn + residual (C-in)
            y = ln_pack(seq[g], q);
            f32x4 t0 = MFMA(af1[0], y, zero4);
            f32x4 t1 = MFMA(af1[1], y, zero4);
            f32x4 t2 = MFMA(af1[2], y, zero4);
            f32x4 t3 = MFMA(af1[3], y, zero4);
            f16x4 u0 = gelu_pack(t0, GC0, GC1, GC2, GC3, GC4, HLF);
            f16x4 u1 = gelu_pack(t1, GC0, GC1, GC2, GC3, GC4, HLF);
            f16x4 u2 = gelu_pack(t2, GC0, GC1, GC2, GC3, GC4, HLF);
            f16x4 u3 = gelu_pack(t3, GC0, GC1, GC2, GC3, GC4, HLF);
            // FFN2 as two 2-deep chains (residual in oA, b2 in oB)
            f32x4 oA = MFMA(af2[0], u0, seq[g]);
            oA = MFMA(af2[1], u1, oA);
            f32x4 oB = MFMA(af2[2], u2, b2f);
            oB = MFMA(af2[3], u3, oB);
            seq[g] = oA + oB;
        }
    }

    // ================= layer 1 (frags scoped; head fused) =====================
    {
        f16x4 aat = __builtin_bit_cast(f16x4, fr[1 * 64 + lane]);
        f16x4 af1[4], aw2c[4], ahead;
#pragma unroll
        for (int m = 0; m < 4; ++m)
            af1[m] = __builtin_bit_cast(f16x4, fr[(6 + m) * 64 + lane]);
#pragma unroll
        for (int c = 0; c < 4; ++c)
            aw2c[c] = __builtin_bit_cast(f16x4, fr[(14 + c) * 64 + lane]);
        ahead = __builtin_bit_cast(f16x4, fr[18 * 64 + lane]);
        float hc = ws[F_HC];
        f32x4 zi = zero4;
        if (lane < 16) zi.x = hc;     // z rides in row 0

#pragma unroll
        for (int g = 0; g < NG; ++g) {
            f16x4 y = ln_pack(seq[g], q);
            seq[g] = MFMA(aat, y, seq[g]);
            y = ln_pack(seq[g], q);
            f32x4 t0 = MFMA(af1[0], y, zero4);
            f32x4 t1 = MFMA(af1[1], y, zero4);
            f32x4 t2 = MFMA(af1[2], y, zero4);
            f32x4 t3 = MFMA(af1[3], y, zero4);
            f16x4 u0 = gelu_pack(t0, GC0, GC1, GC2, GC3, GC4, HLF);
            f16x4 u1 = gelu_pack(t1, GC0, GC1, GC2, GC3, GC4, HLF);
            f16x4 u2 = gelu_pack(t2, GC0, GC1, GC2, GC3, GC4, HLF);
            f16x4 u3 = gelu_pack(t3, GC0, GC1, GC2, GC3, GC4, HLF);
            // z = hc + w2c.up + Wc.seq as two parallel chains (2 + 3 deep)
            f32x4 zcA = MFMA(aw2c[0], u0, zi);
            zcA = MFMA(aw2c[1], u1, zcA);
            f32x4 zcB = MFMA(aw2c[2], u2, zero4);
            zcB = MFMA(aw2c[3], u3, zcB);
            uint2 sh;
            sh.x = pkrtz(seq[g].x, seq[g].y);
            sh.y = pkrtz(seq[g].z, seq[g].w);       // rows>=10 are exact 0
            zcB = MFMA(ahead, __builtin_bit_cast(f16x4, sh), zcB);
            float r = fast_sigmoid(zcA.x + zcB.x);  // row 0, valid in q==0 lanes
            if (q == 0) {
                int e0 = wbase + g * 16 + col;
                if (fullblk) out[e0] = r;           // 16 contiguous f32 per group
                else if (e0 < B) out[e0] = r;
            }
        }
    }
}

extern "C" void kernel_launch(void* const* d_in, const int* in_sizes, int n_in,
                              void* d_out, int out_size, void* d_ws, size_t ws_size,
                              hipStream_t stream) {
    const float* x      = (const float*)d_in[0];
    const float* protos = (const float*)d_in[1];
    // d_in[2..5] = Wq,bq,Wk,bk — dead (seq_len==1 => softmax==1 => o==v)
    const float* Wv   = (const float*)d_in[6];
    const float* bv   = (const float*)d_in[7];
    const float* Wo   = (const float*)d_in[8];
    const float* bo   = (const float*)d_in[9];
    const float* ln1g = (const float*)d_in[10];
    const float* ln1b = (const float*)d_in[11];
    const float* ln2g = (const float*)d_in[12];
    const float* ln2b = (const float*)d_in[13];
    const float* W1   = (const float*)d_in[14];
    const float* b1   = (const float*)d_in[15];
    const float* W2   = (const float*)d_in[16];
    const float* b2   = (const float*)d_in[17];
    const float* Wc   = (const float*)d_in[18];
    const float* bc   = (const float*)d_in[19];
    float* out = (float*)d_out;
    float* ws  = (float*)d_ws;

    // gelu poly coefficients (host-side, identical every call; graph-capture-safe)
    GeluCoef gcoef;
    {
        const double PI = 3.14159265358979323846;
        const double cc = 0.7978845608028654, aa = 0.044715;
        double sv[5], gd[5];
        for (int k = 0; k < 5; ++k) {
            double tk = 1.85 + 1.85 * std::cos((2 * k + 1) * PI / 10.0);
            sv[k] = tk * tk;
            gd[k] = std::tanh(cc * (tk + aa * tk * tk * tk)) / tk;
        }
        for (int j = 1; j < 5; ++j)
            for (int i = 4; i >= j; --i)
                gd[i] = (gd[i] - gd[i - 1]) / (sv[i] - sv[i - j]);
        double c[5] = {0, 0, 0, 0, 0};
        c[0] = gd[4];
        for (int k = 3; k >= 0; --k) {
            for (int i = 4; i >= 1; --i) c[i] = c[i - 1] - sv[k] * c[i];
            c[0] = -sv[k] * c[0] + gd[k];
        }
        for (int i = 0; i < 5; ++i) gcoef.c[i] = (float)(0.5 * c[i]);
    }

    prep2<<<PGRID, 256, 0, stream>>>(Wv, bv, Wo, bo, ln1g, ln1b, ln2g, ln2b,
                                     W1, b1, W2, b2, Wc, bc, ws);

    const int B = in_sizes[0] / 8;
    const int grid = (B + EPB - 1) / EPB;   // 384 elements per block
    hq_mfma<<<grid, BLOCK, 0, stream>>>(x, protos, ws, out, B, gcoef);
}